// Round 14
// baseline (3051.894 us; speedup 1.0000x reference)
//
#include <hip/hip_runtime.h>

typedef __attribute__((ext_vector_type(8))) __bf16 bf16x8;
typedef __attribute__((ext_vector_type(4))) float f32x4;

#define AS1(p) ((const __attribute__((address_space(1))) void*)(uintptr_t)(p))
#define AS3(p) ((__attribute__((address_space(3))) void*)(uint32_t)(uintptr_t)(p))
#define GLD16(gp, lp) __builtin_amdgcn_global_load_lds(AS1(gp), AS3(lp), 16, 0, 0)

static constexpr int Bb = 4, Ss = 2048, Hh = 2048, Ih = 8192;
static constexpr int Mm = Bb * Ss;   // 8192 rows

__device__ __forceinline__ float gelu_exact(float x) {
    return 0.5f * x * (1.0f + erff(x * 0.70710678118654752440f));
}

// ---------------- transpose + fp32->bf16 convert: dst[C][R] = (bf16) src[R][C]
__global__ __launch_bounds__(256) void transpose_cvt(const float* __restrict__ src,
                                                     __bf16* __restrict__ dst,
                                                     int R, int C) {
    __shared__ float tile[32][33];
    const int tx = threadIdx.x, ty = threadIdx.y;
    const int cB = blockIdx.x * 32, rB = blockIdx.y * 32;
#pragma unroll
    for (int i = 0; i < 4; ++i)
        tile[ty + i * 8][tx] = src[(size_t)(rB + ty + i * 8) * C + cB + tx];
    __syncthreads();
#pragma unroll
    for (int i = 0; i < 4; ++i)
        dst[(size_t)(cB + ty + i * 8) * R + rB + tx] = (__bf16)tile[tx][ty + i * 8];
}

// ---------------- fused bias + residual add + LayerNorm -> ln(bf16), ra(bf16)
__global__ __launch_bounds__(256) void fused_ln(const float* __restrict__ input,
                                                const float* __restrict__ residual,
                                                const float* __restrict__ bias,
                                                const float* __restrict__ gamma,
                                                const float* __restrict__ beta,
                                                __bf16* __restrict__ lnb,
                                                __bf16* __restrict__ rab) {
    const int row = blockIdx.x;
    const int tid = threadIdx.x;
    const size_t base = (size_t)row * Hh;
    const int e = tid * 8;

    float4 x0 = *(const float4*)(input + base + e);
    float4 x1 = *(const float4*)(input + base + e + 4);
    float4 r0 = *(const float4*)(residual + base + e);
    float4 r1 = *(const float4*)(residual + base + e + 4);
    float4 b0 = *(const float4*)(bias + e);
    float4 b1 = *(const float4*)(bias + e + 4);

    float s[8];
    s[0] = x0.x + r0.x + b0.x; s[1] = x0.y + r0.y + b0.y;
    s[2] = x0.z + r0.z + b0.z; s[3] = x0.w + r0.w + b0.w;
    s[4] = x1.x + r1.x + b1.x; s[5] = x1.y + r1.y + b1.y;
    s[6] = x1.z + r1.z + b1.z; s[7] = x1.w + r1.w + b1.w;

    float sum = 0.f, sq = 0.f;
#pragma unroll
    for (int j = 0; j < 8; ++j) { sum += s[j]; sq += s[j] * s[j]; }
#pragma unroll
    for (int o = 32; o > 0; o >>= 1) {
        sum += __shfl_xor(sum, o);
        sq  += __shfl_xor(sq, o);
    }
    __shared__ float red[8];
    const int wv = tid >> 6, ln_ = tid & 63;
    if (ln_ == 0) { red[wv] = sum; red[4 + wv] = sq; }
    __syncthreads();
    sum = red[0] + red[1] + red[2] + red[3];
    sq  = red[4] + red[5] + red[6] + red[7];

    const float mu   = sum * (1.0f / Hh);
    const float var  = sq * (1.0f / Hh) - mu * mu;
    const float rstd = rsqrtf(var + 1e-6f);

    float4 g0 = *(const float4*)(gamma + e);
    float4 g1 = *(const float4*)(gamma + e + 4);
    float4 t0 = *(const float4*)(beta + e);
    float4 t1 = *(const float4*)(beta + e + 4);
    float g[8] = {g0.x, g0.y, g0.z, g0.w, g1.x, g1.y, g1.z, g1.w};
    float t[8] = {t0.x, t0.y, t0.z, t0.w, t1.x, t1.y, t1.z, t1.w};

    bf16x8 lv, rv;
#pragma unroll
    for (int j = 0; j < 8; ++j) {
        rv[j] = (__bf16)s[j];
        lv[j] = (__bf16)((s[j] - mu) * rstd * g[j] + t[j]);
    }
    *(bf16x8*)(lnb + base + e) = lv;
    *(bf16x8*)(rab + base + e) = rv;
}

// ---------------- shared GEMM helpers ----------------
#define CFENCE asm volatile("" ::: "memory")
#define BARX   do { CFENCE; __builtin_amdgcn_s_barrier(); CFENCE; } while (0)
#define SP1 __builtin_amdgcn_s_setprio(1)
#define SP0 __builtin_amdgcn_s_setprio(0)
#define LGK0 asm volatile("s_waitcnt lgkmcnt(0)" ::: "memory")
#define VM4 asm volatile("s_waitcnt vmcnt(4)" ::: "memory")
#define VM2 asm volatile("s_waitcnt vmcnt(2)" ::: "memory")
#define VM0 asm volatile("s_waitcnt vmcnt(0)" ::: "memory")

__device__ __forceinline__ void rdF4(bf16x8 (&f)[4][2], const char* p0, const char* p1,
                                     const int off) {
#pragma unroll
    for (int m = 0; m < 4; ++m) {
        f[m][0] = *(const bf16x8*)(p0 + off + m * 2048);
        f[m][1] = *(const bf16x8*)(p1 + off + m * 2048);
    }
}
__device__ __forceinline__ void rdB2(bf16x8 (&bf)[2][2], const char* p0, const char* p1,
                                     const int off) {
#pragma unroll
    for (int n = 0; n < 2; ++n) {
        bf[n][0] = *(const bf16x8*)(p0 + off + n * 2048);
        bf[n][1] = *(const bf16x8*)(p1 + off + n * 2048);
    }
}
__device__ __forceinline__ void stage2(const __bf16* src, __bf16* dst, const size_t row64) {
    GLD16(src, dst);
    GLD16(src + row64, dst + 4096);
}

// ========= GEMM1 (R14): 256x256, BK=32, 64KB LDS -> 2 blocks/CU ============
// out = gelu(A@B^T + bias) -> bf16. 8 waves (2x4), per-wave 128x64 out.
// 2 phases/K-tile: ph1 {MFMA(mh0); read A.mh1; LGK0; BAR} -> all buf-P reads
// drained; ph2 {MFMA(mh1); stage t+2->P; vmcnt(4); BAR; read next A.mh0+B}.
__device__ __forceinline__ void rd4(bf16x8 (&f)[4], const char* p, const int off) {
#pragma unroll
    for (int m = 0; m < 4; ++m)
        f[m] = *(const bf16x8*)(p + off + m * 1024);
}
template <int MH>
__device__ __forceinline__ void mfmaH(const bf16x8 (&a)[4], const bf16x8 (&b)[4],
                                      f32x4 (&acc)[8][4]) {
#pragma unroll
    for (int m = 0; m < 4; ++m)
#pragma unroll
        for (int n = 0; n < 4; ++n)
            acc[MH * 4 + m][n] = __builtin_amdgcn_mfma_f32_16x16x32_bf16(
                a[m], b[n], acc[MH * 4 + m][n], 0, 0, 0);
}

__global__ __launch_bounds__(512, 4) void gemm2cu(const __bf16* __restrict__ A,
                                                  const __bf16* __restrict__ Bt,
                                                  const float* __restrict__ bias,
                                                  __bf16* __restrict__ outH,
                                                  int M, int N, int K) {
    __shared__ __align__(128) __bf16 lds[2 * 2 * 256 * 32];  // 64 KiB

    const int tid = threadIdx.x;
    const int nbx = N >> 8;
    const int nwg = gridDim.x;
    const int cpx = nwg >> 3;
    const int bid = blockIdx.x;
    const int swz = (bid & 7) * cpx + (bid >> 3);
    const int by = swz / nbx, bx = swz - by * nbx;
    const int mBase = by << 8, nBase = bx << 8;

    const int wave = tid >> 6, lane = tid & 63;
    const int wr = wave >> 2, wc = wave & 3;   // 2 x 4 wave grid

    const int NT = K >> 5;       // K-tiles of 32

    // ds_read bases: row-swizzle slot ^= (row&3); row&3 == lane&3 (offsets x16 rows)
    char* ldsc = (char*)lds;
    const int kg = lane >> 4, l4 = lane & 15;
    const int slotX = ((kg ^ (lane & 3)) << 4);
    // A(P) at P*32768 bytes; B(P) at P*32768+16384. A row stride 64 B.
    const int aOff = wr * 8192 + l4 * 64 + slotX;        // + mh*4096 + mi*1024
    const int bOff = 16384 + wc * 4096 + l4 * 64 + slotX; // + nj*1024
    const char* aB[2] = {ldsc + aOff, ldsc + 32768 + aOff};
    const char* bB[2] = {ldsc + bOff, ldsc + 32768 + bOff};

    // staging: 512 thr x 16B = 8KB/pass = 128 rows x 32 cols; 2 passes per mat
    const int srow = tid >> 2;                       // 0..127
    const int scol = (((tid & 3) ^ (srow & 3)) << 3);  // pre-swizzled col slot
    const __bf16* aSt = A + (size_t)(mBase + srow) * K + scol;
    const __bf16* bSt = Bt + (size_t)(nBase + srow) * K + scol;
    __bf16* lw = lds + tid * 8;
    const size_t row128 = (size_t)128 * K;

    // STAGE tile t into buf P: A(2 passes) + B(2 passes) = 4 GLD16/thread
#define STG(P, t)                                                          \
    do {                                                                   \
        GLD16(aSt + (size_t)(t) * 32, lw + (P) * 16384);                   \
        GLD16(aSt + row128 + (size_t)(t) * 32, lw + (P) * 16384 + 4096);   \
        GLD16(bSt + (size_t)(t) * 32, lw + (P) * 16384 + 8192);            \
        GLD16(bSt + row128 + (size_t)(t) * 32, lw + (P) * 16384 + 12288);  \
    } while (0)

    f32x4 acc[8][4] = {};
    bf16x8 afA[4], afB[4], bv[4];

    // Prologue: tile0 staged+landed+broadcast; tile1 staged (4 in flight);
    // pre-read afA (A.mh0), bv (B all-n) of tile0.
    STG(0, 0);
    VM0;
    BARX;
    STG(1, 1);
    rd4(afA, aB[0], 0);
    rd4(bv, bB[0], 0);

#define TILE(P, NP, t)                                                     \
    {                                                                      \
        const bool pf = (t) + 2 < NT;                                      \
        const bool last = (t) == NT - 1;                                   \
        /* ph1: MFMA mh0; read A.mh1; drain own; BAR#1 (all P reads done) */ \
        SP1; mfmaH<0>(afA, bv, acc); SP0;                                  \
        rd4(afB, aB[P], 4096);                                             \
        LGK0;                                                              \
        BARX;                                                              \
        /* ph2: MFMA mh1; stage t+2->P; gate; BAR#2; read next tile */     \
        SP1; mfmaH<1>(afB, bv, acc); SP0;                                  \
        if (pf) { STG(P, (t) + 2); VM4; } else { VM0; }                    \
        BARX;                                                              \
        if (!last) {                                                       \
            rd4(afA, aB[NP], 0);                                           \
            rd4(bv, bB[NP], 0);                                            \
        }                                                                  \
    }

    const int NI = NT >> 1;
    for (int i = 0; i < NI; ++i) {
        TILE(0, 1, 2 * i)
        TILE(1, 0, 2 * i + 1)
    }
#undef TILE
#undef STG

    // epilogue: frag row=(lane>>4)*4+j, col=lane&15
    const int r0 = mBase + wr * 128 + ((lane >> 4) << 2);
    const int c0 = nBase + wc * 64 + (lane & 15);
    float bb[4];
#pragma unroll
    for (int nf = 0; nf < 4; ++nf) bb[nf] = bias[c0 + nf * 16];
#pragma unroll
    for (int mf = 0; mf < 8; ++mf) {
        const int row = r0 + mf * 16;
#pragma unroll
        for (int nf = 0; nf < 4; ++nf) {
            const int col = c0 + nf * 16;
#pragma unroll
            for (int j = 0; j < 4; ++j) {
                const size_t idx = (size_t)(row + j) * N + col;
                outH[idx] = (__bf16)gelu_exact(acc[mf][nf][j] + bb[nf]);
            }
        }
    }
}

// ====== GEMM2 (R9 anchor, proven): out = A@B^T + bias + (float)rab, fp32 ====
template <int MH, int NH>
__device__ __forceinline__ void mfmaQ(const bf16x8 (&a)[4][2], const bf16x8 (&b)[2][2],
                                      f32x4 (&acc)[8][4]) {
#pragma unroll
    for (int ks = 0; ks < 2; ++ks)
#pragma unroll
        for (int m = 0; m < 4; ++m)
#pragma unroll
            for (int n = 0; n < 2; ++n)
                acc[MH * 4 + m][NH * 2 + n] = __builtin_amdgcn_mfma_f32_16x16x32_bf16(
                    a[m][ks], b[n][ks], acc[MH * 4 + m][NH * 2 + n], 0, 0, 0);
}

__global__ __launch_bounds__(512, 2) void gemm256(const __bf16* __restrict__ A,
                                                  const __bf16* __restrict__ Bt,
                                                  const float* __restrict__ bias,
                                                  const __bf16* __restrict__ rab,
                                                  float* __restrict__ outF,
                                                  int M, int N, int K) {
    __shared__ __align__(128) __bf16 lds[2 * 4 * 128 * 64];  // 128 KiB

    const int tid = threadIdx.x;
    const int nbx = N >> 8;
    const int nwg = gridDim.x;
    const int cpx = nwg >> 3;
    const int bid = blockIdx.x;
    const int swz = (bid & 7) * cpx + (bid >> 3);
    const int by = swz / nbx, bx = swz - by * nbx;
    const int mBase = by << 8, nBase = bx << 8;

    const int wave = tid >> 6, lane = tid & 63;
    const int wr = wave >> 2, wc = wave & 3;

    const int NT = K >> 6;
    const int NI = NT >> 1;

    char* ldsc = (char*)lds;
    const int laneCol0 = (((lane >> 4) << 4)) ^ ((lane & 7) << 4);
    const int laneCol1 = laneCol0 ^ 64;
    const int aLaneR = (lane & 15) << 7;
    const int bLaneR = (((wc & 1) << 6) + (lane & 15)) << 7;
    const char* pA[2][2] = {
        {ldsc + (0 * 4 + wr) * 16384 + aLaneR + laneCol0,
         ldsc + (0 * 4 + wr) * 16384 + aLaneR + laneCol1},
        {ldsc + (1 * 4 + wr) * 16384 + aLaneR + laneCol0,
         ldsc + (1 * 4 + wr) * 16384 + aLaneR + laneCol1}};
    const char* pB[2][2] = {
        {ldsc + (0 * 4 + 2 + (wc >> 1)) * 16384 + bLaneR + laneCol0,
         ldsc + (0 * 4 + 2 + (wc >> 1)) * 16384 + bLaneR + laneCol1},
        {ldsc + (1 * 4 + 2 + (wc >> 1)) * 16384 + bLaneR + laneCol0,
         ldsc + (1 * 4 + 2 + (wc >> 1)) * 16384 + bLaneR + laneCol1}};

    const int srow = tid >> 3;
    const int scol = ((tid & 7) ^ (srow & 7)) << 3;
    const __bf16* aSt = A + (size_t)(mBase + srow) * K + scol;
    const __bf16* bSt = Bt + (size_t)(nBase + srow) * K + scol;
    __bf16* lw = lds + tid * 8;
    const size_t row64 = (size_t)64 * K;
    const size_t row128 = (size_t)128 * K;

#define STA(buf, h, t) stage2(aSt + (h) * row128 + (size_t)(t) * 64, lw + ((buf) * 4 + (h)) * 8192, row64)
#define STB(buf, h, t) stage2(bSt + (h) * row128 + (size_t)(t) * 64, lw + ((buf) * 4 + 2 + (h)) * 8192, row64)

    f32x4 acc[8][4] = {};
    bf16x8 af[4][2], b0[2][2], b1[2][2];

    STA(0, 0, 0); STA(0, 1, 0); STB(0, 0, 0); STB(0, 1, 0);
    VM0;
    BARX;
    STB(1, 0, 1); STB(1, 1, 1);
    rdF4(af, pA[0][0], pA[0][1], 0);
    rdB2(b0, pB[0][0], pB[0][1], 0);

    for (int i = 0; i < NI; ++i) {
        const int t0 = 2 * i, t1 = 2 * i + 1;
        const bool pf0 = (t0 + 2 < NT);
        const bool pf1 = (t1 + 2 < NT);
        const bool last = (i == NI - 1);

        SP1; mfmaQ<0, 0>(af, b0, acc); SP0;
        rdB2(b1, pB[0][0], pB[0][1], 4096);
        STA(1, 0, t1);
        BARX;
        SP1; mfmaQ<0, 1>(af, b1, acc); SP0;
        rdF4(af, pA[0][0], pA[0][1], 8192);
        STA(1, 1, t1);
        BARX;
        SP1; mfmaQ<1, 1>(af, b1, acc); SP0;
        if (pf0) { STB(0, 0, t0 + 2); VM2; } else { VM0; }
        BARX;
        SP1; mfmaQ<1, 0>(af, b0, acc); SP0;
        rdF4(af, pA[1][0], pA[1][1], 0);
        rdB2(b0, pB[1][0], pB[1][1], 0);
        if (pf0) STB(0, 1, t0 + 2);
        BARX;
        SP1; mfmaQ<0, 0>(af, b0, acc); SP0;
        rdB2(b1, pB[1][0], pB[1][1], 4096);
        if (pf0) STA(0, 0, t0 + 2);
        BARX;
        SP1; mfmaQ<0, 1>(af, b1, acc); SP0;
        rdF4(af, pA[1][0], pA[1][1], 8192);
        if (pf0) STA(0, 1, t0 + 2);
        BARX;
        SP1; mfmaQ<1, 1>(af, b1, acc); SP0;
        if (pf1) { STB(1, 0, t1 + 2); VM2; } else { VM0; }
        BARX;
        SP1; mfmaQ<1, 0>(af, b0, acc); SP0;
        if (!last) {
            rdF4(af, pA[0][0], pA[0][1], 0);
            rdB2(b0, pB[0][0], pB[0][1], 0);
        }
        if (pf1) STB(1, 1, t1 + 2);
        BARX;
    }
#undef STA
#undef STB

    const int r0 = mBase + wr * 128 + ((lane >> 4) << 2);
    const int c0 = nBase + wc * 64 + (lane & 15);
    float bb[4];
#pragma unroll
    for (int nf = 0; nf < 4; ++nf) bb[nf] = bias[c0 + nf * 16];
#pragma unroll
    for (int mf = 0; mf < 8; ++mf) {
        const int row = r0 + mf * 16;
#pragma unroll
        for (int nf = 0; nf < 4; ++nf) {
            const int col = c0 + nf * 16;
#pragma unroll
            for (int j = 0; j < 4; ++j) {
                const size_t idx = (size_t)(row + j) * N + col;
                outF[idx] = acc[mf][nf][j] + bb[nf] + (float)rab[idx];
            }
        }
    }
}

extern "C" void kernel_launch(void* const* d_in, const int* in_sizes, int n_in,
                              void* d_out, int out_size, void* d_ws, size_t ws_size,
                              hipStream_t stream) {
    const float* input    = (const float*)d_in[0];
    const float* residual = (const float*)d_in[1];
    // d_in[2] residual_norm: unused by the reference path
    const float* bias     = (const float*)d_in[3];
    const float* gamma    = (const float*)d_in[4];
    const float* beta     = (const float*)d_in[5];
    const float* inter_w  = (const float*)d_in[6];  // [H, I]
    const float* inter_b  = (const float*)d_in[7];  // [I]
    const float* output_w = (const float*)d_in[8];  // [I, H]
    const float* output_b = (const float*)d_in[9];  // [H]
    float* out = (float*)d_out;

    // workspace layout (256 MB total)
    __bf16* w1t  = (__bf16*)d_ws;                 // [I][H]  32 MB
    __bf16* w2t  = w1t + (size_t)Ih * Hh;         // [H][I]  32 MB
    __bf16* lnb  = w2t + (size_t)Hh * Ih;         // [M][H]  32 MB
    __bf16* rab  = lnb + (size_t)Mm * Hh;         // [M][H]  32 MB
    __bf16* hbuf = rab + (size_t)Mm * Hh;         // [M][I] 128 MB

    // 1) weights -> bf16, transposed to [N][K]
    transpose_cvt<<<dim3(Ih / 32, Hh / 32), dim3(32, 8), 0, stream>>>(inter_w, w1t, Hh, Ih);
    transpose_cvt<<<dim3(Hh / 32, Ih / 32), dim3(32, 8), 0, stream>>>(output_w, w2t, Ih, Hh);

    // 2) fused bias+residual add + LayerNorm
    fused_ln<<<Mm, 256, 0, stream>>>(input, residual, bias, gamma, beta, lnb, rab);

    // 3) h = gelu(ln @ inter_w + inter_b)  [R14 experiment arm: 2 blocks/CU]
    gemm2cu<<<dim3((Mm / 256) * (Ih / 256)), 512, 0, stream>>>(
        lnb, w1t, inter_b, hbuf, Mm, Ih, Hh);

    // 4) out = h @ output_w + output_b + residual_add  [R9 anchor arm]
    gemm256<<<dim3((Mm / 256) * (Hh / 256)), 512, 0, stream>>>(
        hbuf, w2t, output_b, rab, out, Mm, Hh, Ih);
}

// Round 15
// 598.489 us; speedup vs baseline: 5.0993x; 5.0993x over previous
//
#include <hip/hip_runtime.h>

typedef __attribute__((ext_vector_type(8))) __bf16 bf16x8;
typedef __attribute__((ext_vector_type(4))) float f32x4;

#define AS1(p) ((const __attribute__((address_space(1))) void*)(uintptr_t)(p))
#define AS3(p) ((__attribute__((address_space(3))) void*)(uint32_t)(uintptr_t)(p))
#define GLD16(gp, lp) __builtin_amdgcn_global_load_lds(AS1(gp), AS3(lp), 16, 0, 0)

static constexpr int Bb = 4, Ss = 2048, Hh = 2048, Ih = 8192;
static constexpr int Mm = Bb * Ss;   // 8192 rows

__device__ __forceinline__ float gelu_exact(float x) {
    return 0.5f * x * (1.0f + erff(x * 0.70710678118654752440f));
}

// ---------------- transpose + fp32->bf16 convert: dst[C][R] = (bf16) src[R][C]
__global__ __launch_bounds__(256) void transpose_cvt(const float* __restrict__ src,
                                                     __bf16* __restrict__ dst,
                                                     int R, int C) {
    __shared__ float tile[32][33];
    const int tx = threadIdx.x, ty = threadIdx.y;
    const int cB = blockIdx.x * 32, rB = blockIdx.y * 32;
#pragma unroll
    for (int i = 0; i < 4; ++i)
        tile[ty + i * 8][tx] = src[(size_t)(rB + ty + i * 8) * C + cB + tx];
    __syncthreads();
#pragma unroll
    for (int i = 0; i < 4; ++i)
        dst[(size_t)(cB + ty + i * 8) * R + rB + tx] = (__bf16)tile[tx][ty + i * 8];
}

// ---------------- fused bias + residual add + LayerNorm -> ln(bf16), ra(bf16)
__global__ __launch_bounds__(256) void fused_ln(const float* __restrict__ input,
                                                const float* __restrict__ residual,
                                                const float* __restrict__ bias,
                                                const float* __restrict__ gamma,
                                                const float* __restrict__ beta,
                                                __bf16* __restrict__ lnb,
                                                __bf16* __restrict__ rab) {
    const int row = blockIdx.x;
    const int tid = threadIdx.x;
    const size_t base = (size_t)row * Hh;
    const int e = tid * 8;

    float4 x0 = *(const float4*)(input + base + e);
    float4 x1 = *(const float4*)(input + base + e + 4);
    float4 r0 = *(const float4*)(residual + base + e);
    float4 r1 = *(const float4*)(residual + base + e + 4);
    float4 b0 = *(const float4*)(bias + e);
    float4 b1 = *(const float4*)(bias + e + 4);

    float s[8];
    s[0] = x0.x + r0.x + b0.x; s[1] = x0.y + r0.y + b0.y;
    s[2] = x0.z + r0.z + b0.z; s[3] = x0.w + r0.w + b0.w;
    s[4] = x1.x + r1.x + b1.x; s[5] = x1.y + r1.y + b1.y;
    s[6] = x1.z + r1.z + b1.z; s[7] = x1.w + r1.w + b1.w;

    float sum = 0.f, sq = 0.f;
#pragma unroll
    for (int j = 0; j < 8; ++j) { sum += s[j]; sq += s[j] * s[j]; }
#pragma unroll
    for (int o = 32; o > 0; o >>= 1) {
        sum += __shfl_xor(sum, o);
        sq  += __shfl_xor(sq, o);
    }
    __shared__ float red[8];
    const int wv = tid >> 6, ln_ = tid & 63;
    if (ln_ == 0) { red[wv] = sum; red[4 + wv] = sq; }
    __syncthreads();
    sum = red[0] + red[1] + red[2] + red[3];
    sq  = red[4] + red[5] + red[6] + red[7];

    const float mu   = sum * (1.0f / Hh);
    const float var  = sq * (1.0f / Hh) - mu * mu;
    const float rstd = rsqrtf(var + 1e-6f);

    float4 g0 = *(const float4*)(gamma + e);
    float4 g1 = *(const float4*)(gamma + e + 4);
    float4 t0 = *(const float4*)(beta + e);
    float4 t1 = *(const float4*)(beta + e + 4);
    float g[8] = {g0.x, g0.y, g0.z, g0.w, g1.x, g1.y, g1.z, g1.w};
    float t[8] = {t0.x, t0.y, t0.z, t0.w, t1.x, t1.y, t1.z, t1.w};

    bf16x8 lv, rv;
#pragma unroll
    for (int j = 0; j < 8; ++j) {
        rv[j] = (__bf16)s[j];
        lv[j] = (__bf16)((s[j] - mu) * rstd * g[j] + t[j]);
    }
    *(bf16x8*)(lnb + base + e) = lv;
    *(bf16x8*)(rab + base + e) = rv;
}

// ============ 256x256 bf16 GEMM: R9 schedule + ks-outer MFMA (R10) ==========
// A [M][K] bf16, Bt [N][K] bf16. MODE 0: outH = gelu(A@B^T + bias) bf16.
// MODE 1: outF = A@B^T + bias + (float)rab, fp32.
// Best-measured configuration of the session (591.4 us total). Phase =
// {MFMA(reads from prev phase, compiler-counted lgkm); post-reads for next
// phase; stage-issue; [vmcnt gate at ph3/ph7]; barrier}. 8 barriers/iter.
// Cross-buffer reads sit AFTER the barrier that broadcasts the ph3/ph7 vmcnt
// certificates. Register-neutral: af time-shares aLo/aHi; 64-VGPR frag set.

#define CFENCE asm volatile("" ::: "memory")
#define BARX   do { CFENCE; __builtin_amdgcn_s_barrier(); CFENCE; } while (0)
#define SP1 __builtin_amdgcn_s_setprio(1)
#define SP0 __builtin_amdgcn_s_setprio(0)
#define VM2 asm volatile("s_waitcnt vmcnt(2)" ::: "memory")
#define VM0 asm volatile("s_waitcnt vmcnt(0)" ::: "memory")

__device__ __forceinline__ void rdA(bf16x8 (&af)[4][2], const char* p0, const char* p1,
                                    const int off) {
#pragma unroll
    for (int m = 0; m < 4; ++m) {
        af[m][0] = *(const bf16x8*)(p0 + off + m * 2048);
        af[m][1] = *(const bf16x8*)(p1 + off + m * 2048);
    }
}
__device__ __forceinline__ void rdB(bf16x8 (&bf)[2][2], const char* p0, const char* p1,
                                    const int off) {
#pragma unroll
    for (int n = 0; n < 2; ++n) {
        bf[n][0] = *(const bf16x8*)(p0 + off + n * 2048);
        bf[n][1] = *(const bf16x8*)(p1 + off + n * 2048);
    }
}
template <int MH, int NH>
__device__ __forceinline__ void mfmaQ(const bf16x8 (&a)[4][2], const bf16x8 (&b)[2][2],
                                      f32x4 (&acc)[8][4]) {
    // ks OUTER: 8 independent MFMAs per ks-group.
#pragma unroll
    for (int ks = 0; ks < 2; ++ks)
#pragma unroll
        for (int m = 0; m < 4; ++m)
#pragma unroll
            for (int n = 0; n < 2; ++n)
                acc[MH * 4 + m][NH * 2 + n] = __builtin_amdgcn_mfma_f32_16x16x32_bf16(
                    a[m][ks], b[n][ks], acc[MH * 4 + m][NH * 2 + n], 0, 0, 0);
}
__device__ __forceinline__ void stage2(const __bf16* src, __bf16* dst, const size_t row64) {
    GLD16(src, dst);
    GLD16(src + row64, dst + 4096);
}

template <int MODE>
__global__ __launch_bounds__(512, 2) void gemm256(const __bf16* __restrict__ A,
                                                  const __bf16* __restrict__ Bt,
                                                  const float* __restrict__ bias,
                                                  const __bf16* __restrict__ rab,
                                                  __bf16* __restrict__ outH,
                                                  float* __restrict__ outF,
                                                  int M, int N, int K) {
    __shared__ __align__(128) __bf16 lds[2 * 4 * 128 * 64];  // 128 KiB

    const int tid = threadIdx.x;
    // T1: XCD-aware block swizzle (nwg % 8 == 0 for both our grids)
    const int nbx = N >> 8;
    const int nwg = gridDim.x;
    const int cpx = nwg >> 3;
    const int bid = blockIdx.x;
    const int swz = (bid & 7) * cpx + (bid >> 3);
    const int by = swz / nbx, bx = swz - by * nbx;
    const int mBase = by << 8, nBase = bx << 8;

    const int wave = tid >> 6, lane = tid & 63;
    const int wr = wave >> 2, wc = wave & 3;   // 2 x 4 wave grid

    const int NT = K >> 6;       // K-tiles of 64
    const int NI = NT >> 1;      // 2 tiles per iteration

    // --- ds_read pointers (T2 swizzled): slot ^= (row&7); row&7 == lane&7 here
    char* ldsc = (char*)lds;
    const int laneCol0 = (((lane >> 4) << 4)) ^ ((lane & 7) << 4);       // ks=0
    const int laneCol1 = laneCol0 ^ 64;                                  // ks=1
    const int aLaneR = (lane & 15) << 7;
    const int bLaneR = (((wc & 1) << 6) + (lane & 15)) << 7;
    const char* pA[2][2] = {
        {ldsc + (0 * 4 + wr) * 16384 + aLaneR + laneCol0,
         ldsc + (0 * 4 + wr) * 16384 + aLaneR + laneCol1},
        {ldsc + (1 * 4 + wr) * 16384 + aLaneR + laneCol0,
         ldsc + (1 * 4 + wr) * 16384 + aLaneR + laneCol1}};
    const char* pB[2][2] = {
        {ldsc + (0 * 4 + 2 + (wc >> 1)) * 16384 + bLaneR + laneCol0,
         ldsc + (0 * 4 + 2 + (wc >> 1)) * 16384 + bLaneR + laneCol1},
        {ldsc + (1 * 4 + 2 + (wc >> 1)) * 16384 + bLaneR + laneCol0,
         ldsc + (1 * 4 + 2 + (wc >> 1)) * 16384 + bLaneR + laneCol1}};

    // --- staging addresses: LDS linear, global source col-slot pre-swizzled
    const int srow = tid >> 3;                         // 0..63
    const int scol = ((tid & 7) ^ (srow & 7)) << 3;    // element col (16B slots permuted)
    const __bf16* aSt = A + (size_t)(mBase + srow) * K + scol;
    const __bf16* bSt = Bt + (size_t)(nBase + srow) * K + scol;
    __bf16* lw = lds + tid * 8;
    const size_t row64 = (size_t)64 * K;
    const size_t row128 = (size_t)128 * K;

#define STA(buf, h, t) stage2(aSt + (h) * row128 + (size_t)(t) * 64, lw + ((buf) * 4 + (h)) * 8192, row64)
#define STB(buf, h, t) stage2(bSt + (h) * row128 + (size_t)(t) * 64, lw + ((buf) * 4 + 2 + (h)) * 8192, row64)

    f32x4 acc[8][4] = {};
    bf16x8 af[4][2], b0[2][2], b1[2][2];

    // Prologue: A(t0),B(t0) staged+landed (VM0+BAR broadcast); B(t1) staged;
    // pre-reads aLo(t0), bLo(t0) for ph1's MFMA.
    STA(0, 0, 0); STA(0, 1, 0); STB(0, 0, 0); STB(0, 1, 0);
    VM0;
    BARX;
    STB(1, 0, 1); STB(1, 1, 1);
    rdA(af, pA[0][0], pA[0][1], 0);     // aLo(t0)
    rdB(b0, pB[0][0], pB[0][1], 0);     // bLo(t0)

    for (int i = 0; i < NI; ++i) {
        const int t0 = 2 * i, t1 = 2 * i + 1;
        const bool pf0 = (t0 + 2 < NT);
        const bool pf1 = (t1 + 2 < NT);
        const bool last = (i == NI - 1);

        // ph1: q(0,0) t0; post-read bHi(t0); stage A0(t1)->buf1
        SP1; mfmaQ<0, 0>(af, b0, acc); SP0;
        rdB(b1, pB[0][0], pB[0][1], 4096);
        STA(1, 0, t1);
        BARX;
        // ph2: q(0,1) t0; post-read aHi(t0) (af dead after this MFMA); stage A1(t1)
        SP1; mfmaQ<0, 1>(af, b1, acc); SP0;
        rdA(af, pA[0][0], pA[0][1], 8192);
        STA(1, 1, t1);
        BARX;
        // ph3: q(1,1) t0; stage B0(t0+2)->buf0; GATE (certifies A(t1),B(t1))
        SP1; mfmaQ<1, 1>(af, b1, acc); SP0;
        if (pf0) { STB(0, 0, t0 + 2); VM2; } else { VM0; }
        BARX;
        // ph4: q(1,0) t0; post-reads aLo(t1),bLo(t1) (AFTER gate broadcast);
        //      stage B1(t0+2)->buf0
        SP1; mfmaQ<1, 0>(af, b0, acc); SP0;
        rdA(af, pA[1][0], pA[1][1], 0);
        rdB(b0, pB[1][0], pB[1][1], 0);
        if (pf0) STB(0, 1, t0 + 2);
        BARX;
        // ph5: q(0,0) t1; post-read bHi(t1); stage A0(t0+2)->buf0
        SP1; mfmaQ<0, 0>(af, b0, acc); SP0;
        rdB(b1, pB[1][0], pB[1][1], 4096);
        if (pf0) STA(0, 0, t0 + 2);
        BARX;
        // ph6: q(0,1) t1; post-read aHi(t1); stage A1(t0+2)->buf0
        SP1; mfmaQ<0, 1>(af, b1, acc); SP0;
        rdA(af, pA[1][0], pA[1][1], 8192);
        if (pf0) STA(0, 1, t0 + 2);
        BARX;
        // ph7: q(1,1) t1; stage B0(t1+2)->buf1; GATE (certifies A(t0+2),B(t0+2))
        SP1; mfmaQ<1, 1>(af, b1, acc); SP0;
        if (pf1) { STB(1, 0, t1 + 2); VM2; } else { VM0; }
        BARX;
        // ph8: q(1,0) t1; post-reads aLo,bLo(t0+2); stage B1(t1+2)->buf1
        SP1; mfmaQ<1, 0>(af, b0, acc); SP0;
        if (!last) {
            rdA(af, pA[0][0], pA[0][1], 0);
            rdB(b0, pB[0][0], pB[0][1], 0);
        }
        if (pf1) STB(1, 1, t1 + 2);
        BARX;
    }

    // --- epilogue: C/D layout row=(lane>>4)*4+j, col=lane&15 per 16x16 frag
    const int r0 = mBase + wr * 128 + ((lane >> 4) << 2);
    const int c0 = nBase + wc * 64 + (lane & 15);
    float bb[4];
#pragma unroll
    for (int nf = 0; nf < 4; ++nf) bb[nf] = bias[c0 + nf * 16];
#pragma unroll
    for (int mf = 0; mf < 8; ++mf) {
        const int row = r0 + mf * 16;
#pragma unroll
        for (int nf = 0; nf < 4; ++nf) {
            const int col = c0 + nf * 16;
#pragma unroll
            for (int j = 0; j < 4; ++j) {
                const size_t idx = (size_t)(row + j) * N + col;
                const float v = acc[mf][nf][j] + bb[nf];
                if (MODE == 0) {
                    outH[idx] = (__bf16)gelu_exact(v);
                } else {
                    outF[idx] = v + (float)rab[idx];
                }
            }
        }
    }
#undef STA
#undef STB
}

extern "C" void kernel_launch(void* const* d_in, const int* in_sizes, int n_in,
                              void* d_out, int out_size, void* d_ws, size_t ws_size,
                              hipStream_t stream) {
    const float* input    = (const float*)d_in[0];
    const float* residual = (const float*)d_in[1];
    // d_in[2] residual_norm: unused by the reference path
    const float* bias     = (const float*)d_in[3];
    const float* gamma    = (const float*)d_in[4];
    const float* beta     = (const float*)d_in[5];
    const float* inter_w  = (const float*)d_in[6];  // [H, I]
    const float* inter_b  = (const float*)d_in[7];  // [I]
    const float* output_w = (const float*)d_in[8];  // [I, H]
    const float* output_b = (const float*)d_in[9];  // [H]
    float* out = (float*)d_out;

    // workspace layout (256 MB total)
    __bf16* w1t  = (__bf16*)d_ws;                 // [I][H]  32 MB
    __bf16* w2t  = w1t + (size_t)Ih * Hh;         // [H][I]  32 MB
    __bf16* lnb  = w2t + (size_t)Hh * Ih;         // [M][H]  32 MB
    __bf16* rab  = lnb + (size_t)Mm * Hh;         // [M][H]  32 MB
    __bf16* hbuf = rab + (size_t)Mm * Hh;         // [M][I] 128 MB

    // 1) weights -> bf16, transposed to [N][K]
    transpose_cvt<<<dim3(Ih / 32, Hh / 32), dim3(32, 8), 0, stream>>>(inter_w, w1t, Hh, Ih);
    transpose_cvt<<<dim3(Hh / 32, Ih / 32), dim3(32, 8), 0, stream>>>(output_w, w2t, Ih, Hh);

    // 2) fused bias+residual add + LayerNorm
    fused_ln<<<Mm, 256, 0, stream>>>(input, residual, bias, gamma, beta, lnb, rab);

    // 3) h = gelu(ln @ inter_w + inter_b)   [M=8192, N=I=8192, K=H=2048]
    gemm256<0><<<dim3((Mm / 256) * (Ih / 256)), 512, 0, stream>>>(
        lnb, w1t, inter_b, nullptr, hbuf, nullptr, Mm, Ih, Hh);

    // 4) out = h @ output_w + output_b + residual_add   [M=8192, N=H=2048, K=I=8192]
    gemm256<1><<<dim3((Mm / 256) * (Hh / 256)), 512, 0, stream>>>(
        hbuf, w2t, output_b, rab, nullptr, out, Mm, Hh, Ih);
}

// Round 16
// 590.283 us; speedup vs baseline: 5.1702x; 1.0139x over previous
//
#include <hip/hip_runtime.h>

typedef __attribute__((ext_vector_type(8))) __bf16 bf16x8;
typedef __attribute__((ext_vector_type(4))) float f32x4;

#define AS1(p) ((const __attribute__((address_space(1))) void*)(uintptr_t)(p))
#define AS3(p) ((__attribute__((address_space(3))) void*)(uint32_t)(uintptr_t)(p))
#define GLD16(gp, lp) __builtin_amdgcn_global_load_lds(AS1(gp), AS3(lp), 16, 0, 0)

static constexpr int Bb = 4, Ss = 2048, Hh = 2048, Ih = 8192;
static constexpr int Mm = Bb * Ss;   // 8192 rows

__device__ __forceinline__ float gelu_exact(float x) {
    return 0.5f * x * (1.0f + erff(x * 0.70710678118654752440f));
}

// ---------------- transpose + fp32->bf16 convert: dst[C][R] = (bf16) src[R][C]
__global__ __launch_bounds__(256) void transpose_cvt(const float* __restrict__ src,
                                                     __bf16* __restrict__ dst,
                                                     int R, int C) {
    __shared__ float tile[32][33];
    const int tx = threadIdx.x, ty = threadIdx.y;
    const int cB = blockIdx.x * 32, rB = blockIdx.y * 32;
#pragma unroll
    for (int i = 0; i < 4; ++i)
        tile[ty + i * 8][tx] = src[(size_t)(rB + ty + i * 8) * C + cB + tx];
    __syncthreads();
#pragma unroll
    for (int i = 0; i < 4; ++i)
        dst[(size_t)(cB + ty + i * 8) * R + rB + tx] = (__bf16)tile[tx][ty + i * 8];
}

// ---------------- fused bias + residual add + LayerNorm -> ln(bf16), ra(bf16)
__global__ __launch_bounds__(256) void fused_ln(const float* __restrict__ input,
                                                const float* __restrict__ residual,
                                                const float* __restrict__ bias,
                                                const float* __restrict__ gamma,
                                                const float* __restrict__ beta,
                                                __bf16* __restrict__ lnb,
                                                __bf16* __restrict__ rab) {
    const int row = blockIdx.x;
    const int tid = threadIdx.x;
    const size_t base = (size_t)row * Hh;
    const int e = tid * 8;

    float4 x0 = *(const float4*)(input + base + e);
    float4 x1 = *(const float4*)(input + base + e + 4);
    float4 r0 = *(const float4*)(residual + base + e);
    float4 r1 = *(const float4*)(residual + base + e + 4);
    float4 b0 = *(const float4*)(bias + e);
    float4 b1 = *(const float4*)(bias + e + 4);

    float s[8];
    s[0] = x0.x + r0.x + b0.x; s[1] = x0.y + r0.y + b0.y;
    s[2] = x0.z + r0.z + b0.z; s[3] = x0.w + r0.w + b0.w;
    s[4] = x1.x + r1.x + b1.x; s[5] = x1.y + r1.y + b1.y;
    s[6] = x1.z + r1.z + b1.z; s[7] = x1.w + r1.w + b1.w;

    float sum = 0.f, sq = 0.f;
#pragma unroll
    for (int j = 0; j < 8; ++j) { sum += s[j]; sq += s[j] * s[j]; }
#pragma unroll
    for (int o = 32; o > 0; o >>= 1) {
        sum += __shfl_xor(sum, o);
        sq  += __shfl_xor(sq, o);
    }
    __shared__ float red[8];
    const int wv = tid >> 6, ln_ = tid & 63;
    if (ln_ == 0) { red[wv] = sum; red[4 + wv] = sq; }
    __syncthreads();
    sum = red[0] + red[1] + red[2] + red[3];
    sq  = red[4] + red[5] + red[6] + red[7];

    const float mu   = sum * (1.0f / Hh);
    const float var  = sq * (1.0f / Hh) - mu * mu;
    const float rstd = rsqrtf(var + 1e-6f);

    float4 g0 = *(const float4*)(gamma + e);
    float4 g1 = *(const float4*)(gamma + e + 4);
    float4 t0 = *(const float4*)(beta + e);
    float4 t1 = *(const float4*)(beta + e + 4);
    float g[8] = {g0.x, g0.y, g0.z, g0.w, g1.x, g1.y, g1.z, g1.w};
    float t[8] = {t0.x, t0.y, t0.z, t0.w, t1.x, t1.y, t1.z, t1.w};

    bf16x8 lv, rv;
#pragma unroll
    for (int j = 0; j < 8; ++j) {
        rv[j] = (__bf16)s[j];
        lv[j] = (__bf16)((s[j] - mu) * rstd * g[j] + t[j]);
    }
    *(bf16x8*)(lnb + base + e) = lv;
    *(bf16x8*)(rab + base + e) = rv;
}

// ---------------- shared GEMM helpers ----------------
#define CFENCE asm volatile("" ::: "memory")
#define BARX   do { CFENCE; __builtin_amdgcn_s_barrier(); CFENCE; } while (0)
#define SP1 __builtin_amdgcn_s_setprio(1)
#define SP0 __builtin_amdgcn_s_setprio(0)
#define VM2 asm volatile("s_waitcnt vmcnt(2)" ::: "memory")
#define VM0 asm volatile("s_waitcnt vmcnt(0)" ::: "memory")

__device__ __forceinline__ void rdA(bf16x8 (&af)[4][2], const char* p0, const char* p1,
                                    const int off) {
#pragma unroll
    for (int m = 0; m < 4; ++m) {
        af[m][0] = *(const bf16x8*)(p0 + off + m * 2048);
        af[m][1] = *(const bf16x8*)(p1 + off + m * 2048);
    }
}
template <int M0>
__device__ __forceinline__ void rdA2(bf16x8 (&af)[4][2], const char* p0, const char* p1,
                                     const int off) {
#pragma unroll
    for (int m = M0; m < M0 + 2; ++m) {
        af[m][0] = *(const bf16x8*)(p0 + off + m * 2048);
        af[m][1] = *(const bf16x8*)(p1 + off + m * 2048);
    }
}
__device__ __forceinline__ void rdB(bf16x8 (&bf)[2][2], const char* p0, const char* p1,
                                    const int off) {
#pragma unroll
    for (int n = 0; n < 2; ++n) {
        bf[n][0] = *(const bf16x8*)(p0 + off + n * 2048);
        bf[n][1] = *(const bf16x8*)(p1 + off + n * 2048);
    }
}
template <int MH, int NH>
__device__ __forceinline__ void mfmaQ(const bf16x8 (&a)[4][2], const bf16x8 (&b)[2][2],
                                      f32x4 (&acc)[8][4]) {
#pragma unroll
    for (int ks = 0; ks < 2; ++ks)
#pragma unroll
        for (int m = 0; m < 4; ++m)
#pragma unroll
            for (int n = 0; n < 2; ++n)
                acc[MH * 4 + m][NH * 2 + n] = __builtin_amdgcn_mfma_f32_16x16x32_bf16(
                    a[m][ks], b[n][ks], acc[MH * 4 + m][NH * 2 + n], 0, 0, 0);
}
// Half-burst: m in [M0, M0+2)
template <int MH, int NH, int M0>
__device__ __forceinline__ void mfmaP(const bf16x8 (&a)[4][2], const bf16x8 (&b)[2][2],
                                      f32x4 (&acc)[8][4]) {
#pragma unroll
    for (int ks = 0; ks < 2; ++ks)
#pragma unroll
        for (int m = M0; m < M0 + 2; ++m)
#pragma unroll
            for (int n = 0; n < 2; ++n)
                acc[MH * 4 + m][NH * 2 + n] = __builtin_amdgcn_mfma_f32_16x16x32_bf16(
                    a[m][ks], b[n][ks], acc[MH * 4 + m][NH * 2 + n], 0, 0, 0);
}
__device__ __forceinline__ void stage2(const __bf16* src, __bf16* dst, const size_t row64) {
    GLD16(src, dst);
    GLD16(src + row64, dst + 4096);
}

// Common per-block setup (identical math in both GEMMs).
#define GEMM_SETUP(Aptr, Btptr)                                                          \
    const int tid = threadIdx.x;                                                         \
    const int nbx = N >> 8;                                                              \
    const int nwg = gridDim.x;                                                           \
    const int cpx = nwg >> 3;                                                            \
    const int bid = blockIdx.x;                                                          \
    const int swz = (bid & 7) * cpx + (bid >> 3);                                        \
    const int by = swz / nbx, bx = swz - by * nbx;                                       \
    const int mBase = by << 8, nBase = bx << 8;                                          \
    const int wave = tid >> 6, lane = tid & 63;                                          \
    const int wr = wave >> 2, wc = wave & 3;                                             \
    const int NT = K >> 6;                                                               \
    const int NI = NT >> 1;                                                              \
    char* ldsc = (char*)lds;                                                             \
    const int laneCol0 = (((lane >> 4) << 4)) ^ ((lane & 7) << 4);                       \
    const int laneCol1 = laneCol0 ^ 64;                                                  \
    const int aLaneR = (lane & 15) << 7;                                                 \
    const int bLaneR = (((wc & 1) << 6) + (lane & 15)) << 7;                             \
    const char* pA[2][2] = {                                                             \
        {ldsc + (0 * 4 + wr) * 16384 + aLaneR + laneCol0,                                \
         ldsc + (0 * 4 + wr) * 16384 + aLaneR + laneCol1},                               \
        {ldsc + (1 * 4 + wr) * 16384 + aLaneR + laneCol0,                                \
         ldsc + (1 * 4 + wr) * 16384 + aLaneR + laneCol1}};                              \
    const char* pB[2][2] = {                                                             \
        {ldsc + (0 * 4 + 2 + (wc >> 1)) * 16384 + bLaneR + laneCol0,                     \
         ldsc + (0 * 4 + 2 + (wc >> 1)) * 16384 + bLaneR + laneCol1},                    \
        {ldsc + (1 * 4 + 2 + (wc >> 1)) * 16384 + bLaneR + laneCol0,                     \
         ldsc + (1 * 4 + 2 + (wc >> 1)) * 16384 + bLaneR + laneCol1}};                   \
    const int srow = tid >> 3;                                                           \
    const int scol = ((tid & 7) ^ (srow & 7)) << 3;                                      \
    const __bf16* aSt = (Aptr) + (size_t)(mBase + srow) * K + scol;                      \
    const __bf16* bSt = (Btptr) + (size_t)(nBase + srow) * K + scol;                     \
    __bf16* lw = lds + tid * 8;                                                          \
    const size_t row64 = (size_t)64 * K;                                                 \
    const size_t row128 = (size_t)128 * K;

#define STA(buf, h, t) stage2(aSt + (h) * row128 + (size_t)(t) * 64, lw + ((buf) * 4 + (h)) * 8192, row64)
#define STB(buf, h, t) stage2(bSt + (h) * row128 + (size_t)(t) * 64, lw + ((buf) * 4 + 2 + (h)) * 8192, row64)

// ====== GEMM1 (R16 experiment): R10 schedule + mid-burst read placement =====
// out = gelu(A@B^T + bias) -> bf16. Pure reorder of R10: hazard-free reads
// issue BEFORE the MFMA burst; af-overwriting reads split the burst by m-half
// so they issue ~310 cyc early and drain under the second half's issue.
__global__ __launch_bounds__(512, 2) void gemmS(const __bf16* __restrict__ A,
                                                const __bf16* __restrict__ Bt,
                                                const float* __restrict__ bias,
                                                __bf16* __restrict__ outH,
                                                int M, int N, int K) {
    __shared__ __align__(128) __bf16 lds[2 * 4 * 128 * 64];  // 128 KiB
    GEMM_SETUP(A, Bt)

    f32x4 acc[8][4] = {};
    bf16x8 af[4][2], b0[2][2], b1[2][2];

    // Prologue: A(t0),B(t0) staged+landed; B(t1) staged; pre-reads aLo,bLo(t0).
    STA(0, 0, 0); STA(0, 1, 0); STB(0, 0, 0); STB(0, 1, 0);
    VM0;
    BARX;
    STB(1, 0, 1); STB(1, 1, 1);
    rdA(af, pA[0][0], pA[0][1], 0);
    rdB(b0, pB[0][0], pB[0][1], 0);

    for (int i = 0; i < NI; ++i) {
        const int t0 = 2 * i, t1 = 2 * i + 1;
        const bool pf0 = (t0 + 2 < NT);
        const bool pf1 = (t1 + 2 < NT);

        // ph1: pre-read bHi(t0) [no hazard]; q00; stage A0(t1)
        rdB(b1, pB[0][0], pB[0][1], 4096);
        SP1; mfmaQ<0, 0>(af, b0, acc); SP0;
        STA(1, 0, t1);
        BARX;
        // ph2: q01 split; af<-aHi(t0) mid-burst; stage A1(t1)
        SP1; mfmaP<0, 1, 0>(af, b1, acc);
        rdA2<0>(af, pA[0][0], pA[0][1], 8192);
        mfmaP<0, 1, 2>(af, b1, acc); SP0;
        rdA2<2>(af, pA[0][0], pA[0][1], 8192);
        STA(1, 1, t1);
        BARX;
        // ph3: q11; stage B0(t0+2); GATE (certifies A(t1),B(t1))
        SP1; mfmaQ<1, 1>(af, b1, acc); SP0;
        if (pf0) { STB(0, 0, t0 + 2); VM2; } else { VM0; }
        BARX;
        // ph4: q10 split; af<-aLo(t1) mid-burst; b0<-bLo(t1) post; stage B1(t0+2)
        SP1; mfmaP<1, 0, 0>(af, b0, acc);
        rdA2<0>(af, pA[1][0], pA[1][1], 0);
        mfmaP<1, 0, 2>(af, b0, acc); SP0;
        rdA2<2>(af, pA[1][0], pA[1][1], 0);
        rdB(b0, pB[1][0], pB[1][1], 0);
        if (pf0) STB(0, 1, t0 + 2);
        BARX;
        // ph5: pre-read bHi(t1); q00; stage A0(t0+2)
        rdB(b1, pB[1][0], pB[1][1], 4096);
        SP1; mfmaQ<0, 0>(af, b0, acc); SP0;
        if (pf0) STA(0, 0, t0 + 2);
        BARX;
        // ph6: q01 split; af<-aHi(t1) mid-burst; stage A1(t0+2)
        SP1; mfmaP<0, 1, 0>(af, b1, acc);
        rdA2<0>(af, pA[1][0], pA[1][1], 8192);
        mfmaP<0, 1, 2>(af, b1, acc); SP0;
        rdA2<2>(af, pA[1][0], pA[1][1], 8192);
        if (pf0) STA(0, 1, t0 + 2);
        BARX;
        // ph7: q11; stage B0(t1+2); GATE (certifies A(t0+2),B(t0+2))
        SP1; mfmaQ<1, 1>(af, b1, acc); SP0;
        if (pf1) { STB(1, 0, t1 + 2); VM2; } else { VM0; }
        BARX;
        // ph8: q10 split; af<-aLo(t0+2) mid-burst; b0<-bLo(t0+2) post; stage B1
        SP1; mfmaP<1, 0, 0>(af, b0, acc);
        rdA2<0>(af, pA[0][0], pA[0][1], 0);
        mfmaP<1, 0, 2>(af, b0, acc); SP0;
        rdA2<2>(af, pA[0][0], pA[0][1], 0);
        rdB(b0, pB[0][0], pB[0][1], 0);
        if (pf1) STB(1, 1, t1 + 2);
        BARX;
    }

    const int r0 = mBase + wr * 128 + ((lane >> 4) << 2);
    const int c0 = nBase + wc * 64 + (lane & 15);
    float bb[4];
#pragma unroll
    for (int nf = 0; nf < 4; ++nf) bb[nf] = bias[c0 + nf * 16];
#pragma unroll
    for (int mf = 0; mf < 8; ++mf) {
        const int row = r0 + mf * 16;
#pragma unroll
        for (int nf = 0; nf < 4; ++nf) {
            const int col = c0 + nf * 16;
#pragma unroll
            for (int j = 0; j < 4; ++j) {
                const size_t idx = (size_t)(row + j) * N + col;
                outH[idx] = (__bf16)gelu_exact(acc[mf][nf][j] + bb[nf]);
            }
        }
    }
}

// ====== GEMM2 (R10 anchor, proven): out = A@B^T + bias + (float)rab, fp32 ===
__global__ __launch_bounds__(512, 2) void gemm256(const __bf16* __restrict__ A,
                                                  const __bf16* __restrict__ Bt,
                                                  const float* __restrict__ bias,
                                                  const __bf16* __restrict__ rab,
                                                  float* __restrict__ outF,
                                                  int M, int N, int K) {
    __shared__ __align__(128) __bf16 lds[2 * 4 * 128 * 64];  // 128 KiB
    GEMM_SETUP(A, Bt)

    f32x4 acc[8][4] = {};
    bf16x8 af[4][2], b0[2][2], b1[2][2];

    STA(0, 0, 0); STA(0, 1, 0); STB(0, 0, 0); STB(0, 1, 0);
    VM0;
    BARX;
    STB(1, 0, 1); STB(1, 1, 1);
    rdA(af, pA[0][0], pA[0][1], 0);
    rdB(b0, pB[0][0], pB[0][1], 0);

    for (int i = 0; i < NI; ++i) {
        const int t0 = 2 * i, t1 = 2 * i + 1;
        const bool pf0 = (t0 + 2 < NT);
        const bool pf1 = (t1 + 2 < NT);
        const bool last = (i == NI - 1);

        SP1; mfmaQ<0, 0>(af, b0, acc); SP0;
        rdB(b1, pB[0][0], pB[0][1], 4096);
        STA(1, 0, t1);
        BARX;
        SP1; mfmaQ<0, 1>(af, b1, acc); SP0;
        rdA(af, pA[0][0], pA[0][1], 8192);
        STA(1, 1, t1);
        BARX;
        SP1; mfmaQ<1, 1>(af, b1, acc); SP0;
        if (pf0) { STB(0, 0, t0 + 2); VM2; } else { VM0; }
        BARX;
        SP1; mfmaQ<1, 0>(af, b0, acc); SP0;
        rdA(af, pA[1][0], pA[1][1], 0);
        rdB(b0, pB[1][0], pB[1][1], 0);
        if (pf0) STB(0, 1, t0 + 2);
        BARX;
        SP1; mfmaQ<0, 0>(af, b0, acc); SP0;
        rdB(b1, pB[1][0], pB[1][1], 4096);
        if (pf0) STA(0, 0, t0 + 2);
        BARX;
        SP1; mfmaQ<0, 1>(af, b1, acc); SP0;
        rdA(af, pA[1][0], pA[1][1], 8192);
        if (pf0) STA(0, 1, t0 + 2);
        BARX;
        SP1; mfmaQ<1, 1>(af, b1, acc); SP0;
        if (pf1) { STB(1, 0, t1 + 2); VM2; } else { VM0; }
        BARX;
        SP1; mfmaQ<1, 0>(af, b0, acc); SP0;
        if (!last) {
            rdA(af, pA[0][0], pA[0][1], 0);
            rdB(b0, pB[0][0], pB[0][1], 0);
        }
        if (pf1) STB(1, 1, t1 + 2);
        BARX;
    }

    const int r0 = mBase + wr * 128 + ((lane >> 4) << 2);
    const int c0 = nBase + wc * 64 + (lane & 15);
    float bb[4];
#pragma unroll
    for (int nf = 0; nf < 4; ++nf) bb[nf] = bias[c0 + nf * 16];
#pragma unroll
    for (int mf = 0; mf < 8; ++mf) {
        const int row = r0 + mf * 16;
#pragma unroll
        for (int nf = 0; nf < 4; ++nf) {
            const int col = c0 + nf * 16;
#pragma unroll
            for (int j = 0; j < 4; ++j) {
                const size_t idx = (size_t)(row + j) * N + col;
                outF[idx] = acc[mf][nf][j] + bb[nf] + (float)rab[idx];
            }
        }
    }
}

extern "C" void kernel_launch(void* const* d_in, const int* in_sizes, int n_in,
                              void* d_out, int out_size, void* d_ws, size_t ws_size,
                              hipStream_t stream) {
    const float* input    = (const float*)d_in[0];
    const float* residual = (const float*)d_in[1];
    // d_in[2] residual_norm: unused by the reference path
    const float* bias     = (const float*)d_in[3];
    const float* gamma    = (const float*)d_in[4];
    const float* beta     = (const float*)d_in[5];
    const float* inter_w  = (const float*)d_in[6];  // [H, I]
    const float* inter_b  = (const float*)d_in[7];  // [I]
    const float* output_w = (const float*)d_in[8];  // [I, H]
    const float* output_b = (const float*)d_in[9];  // [H]
    float* out = (float*)d_out;

    // workspace layout (256 MB total)
    __bf16* w1t  = (__bf16*)d_ws;                 // [I][H]  32 MB
    __bf16* w2t  = w1t + (size_t)Ih * Hh;         // [H][I]  32 MB
    __bf16* lnb  = w2t + (size_t)Hh * Ih;         // [M][H]  32 MB
    __bf16* rab  = lnb + (size_t)Mm * Hh;         // [M][H]  32 MB
    __bf16* hbuf = rab + (size_t)Mm * Hh;         // [M][I] 128 MB

    // 1) weights -> bf16, transposed to [N][K]
    transpose_cvt<<<dim3(Ih / 32, Hh / 32), dim3(32, 8), 0, stream>>>(inter_w, w1t, Hh, Ih);
    transpose_cvt<<<dim3(Hh / 32, Ih / 32), dim3(32, 8), 0, stream>>>(output_w, w2t, Ih, Hh);

    // 2) fused bias+residual add + LayerNorm
    fused_ln<<<Mm, 256, 0, stream>>>(input, residual, bias, gamma, beta, lnb, rab);

    // 3) h = gelu(ln @ inter_w + inter_b)  [R16 experiment arm]
    gemmS<<<dim3((Mm / 256) * (Ih / 256)), 512, 0, stream>>>(
        lnb, w1t, inter_b, hbuf, Mm, Ih, Hh);

    // 4) out = h @ output_w + output_b + residual_add  [R10 anchor arm]
    gemm256<<<dim3((Mm / 256) * (Hh / 256)), 512, 0, stream>>>(
        hbuf, w2t, output_b, rab, out, Mm, Hh, Ih);
}